// Round 2
// 5890.027 us; speedup vs baseline: 1.2628x; 1.2628x over previous
//
#include <hip/hip_runtime.h>
#include <hip/hip_bf16.h>
#include <math.h>

#define EMBED  512
#define HIDDEN 512
#define NGATE  2048
#define OUTF   100
#define BATCH  500
#define TSTEPS 256
#define XROW   (TSTEPS * EMBED)     // 131072 floats per batch row of x
#define MPAD   512                  // batch padded to 512
#define WHALF  1048576              // frag elems per W matrix: 64nt * 32k16 * 64lane * 8
#define NSLOT  262144               // bf16 elems per h/x time-slot: 16mt * 2048 * 8
#define GRIDP  256                  // persistent grid: 16 ht x 16 mt

typedef __bf16 v8bf   __attribute__((ext_vector_type(8)));
typedef float  f32x16 __attribute__((ext_vector_type(16)));

__device__ __forceinline__ float sigm_(float v) { return 1.f / (1.f + __expf(-v)); }
__device__ __forceinline__ float tanh_(float v) { return 1.f - 2.f / (__expf(2.f * v) + 1.f); }

// async global->LDS, 16B per lane; LDS dest is wave-uniform base + lane*16.
__device__ __forceinline__ void dma16(const __bf16* g, __bf16* l) {
    __builtin_amdgcn_global_load_lds(
        (const __attribute__((address_space(1))) unsigned int*)g,
        (__attribute__((address_space(3))) unsigned int*)l, 16, 0, 0);
}

// ---------------------------------------------------------------------------
// One-time: W_ih / W_hh (fp32 (2048,512)) -> bf16 MFMA B-fragment order:
//   wf[which][nt][k16][lane][8], row = nt*32+(lane&31), k = k16*16+(lane>>5)*8+slot
// ---------------------------------------------------------------------------
__global__ __launch_bounds__(256) void convert_w(
    const float* __restrict__ Wih, const float* __restrict__ Whh,
    __bf16* __restrict__ wf)
{
    const int idx   = blockIdx.x * 256 + threadIdx.x;   // 0..262143
    const int which = idx >> 17;
    const int s     = idx & 131071;                     // (nt*32 + k16)*64 + lane
    const int lane  = s & 63;
    const int k16   = (s >> 6) & 31;
    const int nt    = s >> 11;
    const int row   = nt * 32 + (lane & 31);
    const int k     = k16 * 16 + ((lane >> 5) << 3);
    const float* W  = which ? Whh : Wih;
    const float* p  = W + (long)row * 512 + k;
    const float4 f0 = *(const float4*)p;
    const float4 f1 = *(const float4*)(p + 4);
    v8bf v;
    v[0] = (__bf16)f0.x; v[1] = (__bf16)f0.y; v[2] = (__bf16)f0.z; v[3] = (__bf16)f0.w;
    v[4] = (__bf16)f1.x; v[5] = (__bf16)f1.y; v[6] = (__bf16)f1.z; v[7] = (__bf16)f1.w;
    *(v8bf*)&wf[(long)which * WHALF + (long)s * 8] = v;
}

// W_fc (100,512) fp32 -> bf16 frags, N padded to 128 (rows >=100 zeroed).
__global__ __launch_bounds__(256) void convert_wfc(
    const float* __restrict__ Wfc, __bf16* __restrict__ wfcf)
{
    const int s    = blockIdx.x * 256 + threadIdx.x;    // 0..8191
    const int lane = s & 63;
    const int k16  = (s >> 6) & 31;
    const int nt   = s >> 11;                           // 0..3
    const int row  = nt * 32 + (lane & 31);
    const int k    = k16 * 16 + ((lane >> 5) << 3);
    v8bf v;
    if (row < OUTF) {
        const float* p  = Wfc + (long)row * HIDDEN + k;
        const float4 f0 = *(const float4*)p;
        const float4 f1 = *(const float4*)(p + 4);
        v[0] = (__bf16)f0.x; v[1] = (__bf16)f0.y; v[2] = (__bf16)f0.z; v[3] = (__bf16)f0.w;
        v[4] = (__bf16)f1.x; v[5] = (__bf16)f1.y; v[6] = (__bf16)f1.z; v[7] = (__bf16)f1.w;
    } else {
        #pragma unroll
        for (int j = 0; j < 8; ++j) v[j] = (__bf16)0.f;
    }
    *(v8bf*)&wfcf[(size_t)s * 8] = v;
}

// Optional one-time: x (fp32) -> bf16 A-fragment order per (t, mt) slot.
__global__ __launch_bounds__(256) void convert_x(
    const float* __restrict__ x, __bf16* __restrict__ xbf)
{
    const int idx = blockIdx.x * 256 + threadIdx.x;     // 0 .. 256*16*2048-1
    const int ts  = idx >> 15;
    const int rem = idx & 32767;
    const int mt  = rem >> 11;
    const int s   = rem & 2047;
    const int ln  = s & 63;
    const int k16 = s >> 6;
    const int r   = ln & 31;
    const int b   = mt * 32 + r;
    const int k   = k16 * 16 + ((ln >> 5) << 3);
    v8bf v;
    if (b < BATCH) {
        const float* p  = x + (size_t)b * XROW + (size_t)ts * EMBED + k;
        const float4 f0 = *(const float4*)p;
        const float4 f1 = *(const float4*)(p + 4);
        v[0] = (__bf16)f0.x; v[1] = (__bf16)f0.y; v[2] = (__bf16)f0.z; v[3] = (__bf16)f0.w;
        v[4] = (__bf16)f1.x; v[5] = (__bf16)f1.y; v[6] = (__bf16)f1.z; v[7] = (__bf16)f1.w;
    } else {
        #pragma unroll
        for (int j = 0; j < 8; ++j) v[j] = (__bf16)0.f;
    }
    *(v8bf*)&xbf[(size_t)idx * 8] = v;
}

// stage x(ts) tile for batch-tile mt into Abuf, fragment order.
__device__ __forceinline__ void stage_x_frag(
    const float* __restrict__ x, const __bf16* __restrict__ xbf, int use_xbf,
    __bf16* Abuf, int tid, int w, int lane, int mt, int ts)
{
    if (use_xbf) {
        const __bf16* xsrc = xbf + (size_t)ts * NSLOT + (size_t)mt * 16384;
        #pragma unroll
        for (int it = 0; it < 8; ++it) {
            const int sb = it * 256 + w * 64;
            dma16(xsrc + (size_t)(sb + lane) * 8, &Abuf[sb * 8]);
        }
    } else {
        #pragma unroll
        for (int it = 0; it < 8; ++it) {
            const int s   = it * 256 + tid;
            const int k16 = s >> 6, ln = s & 63;
            const int r   = ln & 31;
            const int b   = mt * 32 + r;
            const int k   = k16 * 16 + ((ln >> 5) << 3);
            v8bf v;
            if (b < BATCH) {
                const float* p  = x + (size_t)b * XROW + (size_t)ts * EMBED + k;
                const float4 f0 = *(const float4*)p;
                const float4 f1 = *(const float4*)(p + 4);
                v[0] = (__bf16)f0.x; v[1] = (__bf16)f0.y; v[2] = (__bf16)f0.z; v[3] = (__bf16)f0.w;
                v[4] = (__bf16)f1.x; v[5] = (__bf16)f1.y; v[6] = (__bf16)f1.z; v[7] = (__bf16)f1.w;
            } else {
                #pragma unroll
                for (int j = 0; j < 8; ++j) v[j] = (__bf16)0.f;
            }
            *(v8bf*)&Abuf[s * 8] = v;
        }
    }
}

// ---------------------------------------------------------------------------
// Persistent LSTM: one PLAIN launch (grid 256 = #CUs) runs all 256 steps.
// bid = (ht = bid>>4) x (mt = bid&15); block = 4 waves, wave w = gate w.
// W_hh frags in registers; c in thread registers; h exchanged via global
// fragment-ordered ring hf[t] with per-mt-group (16-block) atomic barriers.
// Co-residency: 50 KB LDS / ~250 VGPR allow >=2 blocks/CU, grid == #CUs, so
// all 256 blocks dispatch immediately; sync is only within 16-block groups.
// ---------------------------------------------------------------------------
__global__ __launch_bounds__(256, 1) void lstm_persist(
    const float*  __restrict__ x,
    const __bf16* __restrict__ wf,
    const float*  __restrict__ bih, const float* __restrict__ bhh,
    __bf16* __restrict__ hf,          // 257 slots: slot t = h_{t-1}, slot 0 zeroed
    const __bf16* __restrict__ xbf,   // optional frag-ordered x
    unsigned* __restrict__ cnt,       // 16 groups * 32 u32 (128B stride)
    int use_xbf)
{
    __shared__ __align__(16) __bf16 Abuf[2048 * 8];   // 32 KB frag-ordered A tile
    __shared__ __align__(16) float  Gs[4][32][36];    // gate exchange

    const int tid  = threadIdx.x;
    const int lane = tid & 63;
    const int w    = tid >> 6;
    const int bid  = blockIdx.x;
    const int mt   = bid & 15;
    const int ht   = bid >> 4;

    unsigned* cnt_mt = cnt + mt * 32;

    // hoisted per-thread constants
    const int col  = lane & 31;
    const int half = lane >> 5;
    const int gidx = w * 512 + ht * 32 + col;
    const float bias = bih[gidx] + bhh[gidx];

    const int cm  = tid >> 3;              // batch row in tile
    const int cnb = (tid & 7) << 2;        // hidden col base (within ht tile)
    const int hid = ht * 32 + cnb;
    const size_t hwoff = ((size_t)mt * 2048 + (size_t)(hid >> 4) * 64
                          + (size_t)(cm + (((hid >> 3) & 1) << 5))) * 8 + (hid & 7);

    // preload W_hh fragments into registers (128 VGPR)
    const __bf16* wfh = wf + WHALF + (size_t)(w * 16 + ht) * 16384;
    const __bf16* wfi = wf + (size_t)(w * 16 + ht) * 16384;
    v8bf whh[32];
    #pragma unroll
    for (int k16 = 0; k16 < 32; ++k16)
        whh[k16] = *(const v8bf*)&wfh[k16 * 512 + lane * 8];

    float4 cv = make_float4(0.f, 0.f, 0.f, 0.f);

    // prologue: xacc for t=0
    f32x16 xacc;
    #pragma unroll
    for (int j = 0; j < 16; ++j) xacc[j] = 0.f;
    stage_x_frag(x, xbf, use_xbf, Abuf, tid, w, lane, mt, 0);
    __syncthreads();
    #pragma unroll
    for (int k16 = 0; k16 < 32; ++k16) {
        const v8bf a = *(const v8bf*)&Abuf[(k16 * 64 + lane) * 8];
        const v8bf b = *(const v8bf*)&wfi[k16 * 512 + lane * 8];
        xacc = __builtin_amdgcn_mfma_f32_32x32x16_bf16(a, b, xacc, 0, 0, 0);
    }

    #pragma unroll 1
    for (int t = 0; t < TSTEPS; ++t) {
        // ---- wait: h_{t-1} (slot t) published by all 16 blocks of group mt
        if (t > 0 && tid == 0) {
            const unsigned target = 16u * (unsigned)t;
            unsigned iters = 0;
            while (__hip_atomic_load(cnt_mt, __ATOMIC_RELAXED, __HIP_MEMORY_SCOPE_AGENT) < target) {
                __builtin_amdgcn_s_sleep(2);
                if (++iters > 50000000u) break;    // escape hatch: never hang the bench
            }
        }
        __syncthreads();                               // also Abuf WAR guard
        if (t > 0) __builtin_amdgcn_fence(__ATOMIC_ACQUIRE, "agent");

        // ---- (a) DMA-stage h_{t-1} frags
        {
            const __bf16* hsrc = hf + (size_t)t * NSLOT + (size_t)mt * 16384;
            #pragma unroll
            for (int it = 0; it < 8; ++it) {
                const int sb = it * 256 + w * 64;
                dma16(hsrc + (size_t)(sb + lane) * 8, &Abuf[sb * 8]);
            }
        }
        __syncthreads();                               // vmcnt drain -> data in LDS

        // ---- (b) acc = x-part + h·W_hh (W_hh from registers)
        f32x16 acc = xacc;
        #pragma unroll
        for (int k16 = 0; k16 < 32; ++k16) {
            const v8bf a = *(const v8bf*)&Abuf[(k16 * 64 + lane) * 8];
            acc = __builtin_amdgcn_mfma_f32_32x32x16_bf16(a, whh[k16], acc, 0, 0, 0);
        }

        // ---- (c) gate exchange + cell update + h write
        #pragma unroll
        for (int r = 0; r < 16; ++r) {
            const int mr = (r & 3) + 8 * (r >> 2) + 4 * half;
            Gs[w][mr][col] = acc[r] + bias;
        }
        __syncthreads();
        {
            const float4 gi = *(const float4*)&Gs[0][cm][cnb];
            const float4 gf = *(const float4*)&Gs[1][cm][cnb];
            const float4 gg = *(const float4*)&Gs[2][cm][cnb];
            const float4 go = *(const float4*)&Gs[3][cm][cnb];
            float4 hv;
            const float i0 = sigm_(gi.x), f0 = sigm_(gf.x), g0 = tanh_(gg.x), o0 = sigm_(go.x);
            cv.x = f0 * cv.x + i0 * g0; hv.x = o0 * tanh_(cv.x);
            const float i1 = sigm_(gi.y), f1 = sigm_(gf.y), g1 = tanh_(gg.y), o1 = sigm_(go.y);
            cv.y = f1 * cv.y + i1 * g1; hv.y = o1 * tanh_(cv.y);
            const float i2 = sigm_(gi.z), f2 = sigm_(gf.z), g2 = tanh_(gg.z), o2 = sigm_(go.z);
            cv.z = f2 * cv.z + i2 * g2; hv.z = o2 * tanh_(cv.z);
            const float i3 = sigm_(gi.w), f3 = sigm_(gf.w), g3 = tanh_(gg.w), o3 = sigm_(go.w);
            cv.w = f3 * cv.w + i3 * g3; hv.w = o3 * tanh_(cv.w);
            union { uint2 u; __bf16 b4[4]; } z4;
            z4.b4[0] = (__bf16)hv.x; z4.b4[1] = (__bf16)hv.y;
            z4.b4[2] = (__bf16)hv.z; z4.b4[3] = (__bf16)hv.w;
            *(uint2*)&hf[(size_t)(t + 1) * NSLOT + hwoff] = z4.u;
        }
        __syncthreads();                               // all hf stores drained (vmcnt0 @ barrier)
        if (tid == 0) {
            __builtin_amdgcn_fence(__ATOMIC_RELEASE, "agent");
            __hip_atomic_fetch_add(cnt_mt, 1u, __ATOMIC_RELEASE, __HIP_MEMORY_SCOPE_AGENT);
        }

        // ---- (d) x-part for t+1 (off the h critical path; peers arrive meanwhile)
        if (t + 1 < TSTEPS) {
            stage_x_frag(x, xbf, use_xbf, Abuf, tid, w, lane, mt, t + 1);
            __syncthreads();
            f32x16 xa;
            #pragma unroll
            for (int j = 0; j < 16; ++j) xa[j] = 0.f;
            #pragma unroll
            for (int k16 = 0; k16 < 32; ++k16) {
                const v8bf a = *(const v8bf*)&Abuf[(k16 * 64 + lane) * 8];
                const v8bf b = *(const v8bf*)&wfi[k16 * 512 + lane * 8];
                xa = __builtin_amdgcn_mfma_f32_32x32x16_bf16(a, b, xa, 0, 0, 0);
            }
            xacc = xa;
        }
    }
}

// ---------------------------------------------------------------------------
// Deferred FC head: one launch for all (b,t). out = sigmoid(h @ Wfc^T + bfc).
// Block (t, mt): A = hf slot t+1 (frag order, DMA), B = wfcf (N padded 128).
// ---------------------------------------------------------------------------
__global__ __launch_bounds__(256) void fc_mfma(
    const __bf16* __restrict__ hf, const __bf16* __restrict__ wfcf,
    const float* __restrict__ bfc, float* __restrict__ out)
{
    __shared__ __align__(16) __bf16 Abuf[2048 * 8];
    __shared__ __align__(16) float  Fs[32][132];

    const int tid  = threadIdx.x;
    const int lane = tid & 63;
    const int w    = tid >> 6;
    const int t    = blockIdx.x;
    const int mt   = blockIdx.y;

    const __bf16* hsrc = hf + (size_t)(t + 1) * NSLOT + (size_t)mt * 16384;
    #pragma unroll
    for (int it = 0; it < 8; ++it) {
        const int sb = it * 256 + w * 64;
        dma16(hsrc + (size_t)(sb + lane) * 8, &Abuf[sb * 8]);
    }
    __syncthreads();

    f32x16 acc;
    #pragma unroll
    for (int j = 0; j < 16; ++j) acc[j] = 0.f;
    const __bf16* wfw = wfcf + (size_t)w * 16384;
    #pragma unroll
    for (int k16 = 0; k16 < 32; ++k16) {
        const v8bf a = *(const v8bf*)&Abuf[(k16 * 64 + lane) * 8];
        const v8bf b = *(const v8bf*)&wfw[k16 * 512 + lane * 8];
        acc = __builtin_amdgcn_mfma_f32_32x32x16_bf16(a, b, acc, 0, 0, 0);
    }

    const int col = lane & 31, half = lane >> 5;
    #pragma unroll
    for (int r = 0; r < 16; ++r) {
        const int mr = (r & 3) + 8 * (r >> 2) + 4 * half;
        Fs[mr][w * 32 + col] = acc[r];
    }
    __syncthreads();

    const int mr = tid >> 3;
    const int b  = mt * 32 + mr;
    if (b < BATCH) {
        const int c0 = (tid & 7) * 16;
        float* ob = out + ((size_t)b * TSTEPS + t) * OUTF;
        #pragma unroll
        for (int j = 0; j < 4; ++j) {
            const int o = c0 + j * 4;
            if (o < OUTF) {
                const float4 v  = *(const float4*)&Fs[mr][o];
                const float4 bv = *(const float4*)&bfc[o];
                float4 r4;
                r4.x = sigm_(v.x + bv.x); r4.y = sigm_(v.y + bv.y);
                r4.z = sigm_(v.z + bv.z); r4.w = sigm_(v.w + bv.w);
                *(float4*)&ob[o] = r4;
            }
        }
    }
}

// ===========================================================================
// Fallback path (verified round-0 structure): per-step gates_cell + fc_kernel.
// Used when ws_size cannot hold the 257-slot hf ring.
// ===========================================================================
__global__ __launch_bounds__(256) void gates_cell(
    const float*  __restrict__ x,
    const __bf16* __restrict__ hbf_in,
    const __bf16* __restrict__ wf,
    const float*  __restrict__ bih, const float* __restrict__ bhh,
    float* __restrict__ c,
    float* __restrict__ h,
    __bf16* __restrict__ hbf_out,
    int t)
{
    __shared__ __bf16 Abuf[32 * 64 * 8];
    __shared__ float  Gs[4][32][36];

    const int tid  = threadIdx.x;
    const int lane = tid & 63;
    const int w    = tid >> 6;
    const int ht   = blockIdx.x;
    const int mt   = blockIdx.y;

    #pragma unroll
    for (int it = 0; it < 8; ++it) {
        const int s   = it * 256 + tid;
        const int k16 = s >> 6, ln = s & 63;
        const int r   = ln & 31;
        const int b   = mt * 32 + r;
        const int k   = k16 * 16 + ((ln >> 5) << 3);
        v8bf v;
        if (b < BATCH) {
            const float* p = x + (long)b * XROW + (long)t * EMBED + k;
            const float4 f0 = *(const float4*)p;
            const float4 f1 = *(const float4*)(p + 4);
            v[0] = (__bf16)f0.x; v[1] = (__bf16)f0.y; v[2] = (__bf16)f0.z; v[3] = (__bf16)f0.w;
            v[4] = (__bf16)f1.x; v[5] = (__bf16)f1.y; v[6] = (__bf16)f1.z; v[7] = (__bf16)f1.w;
        } else {
            #pragma unroll
            for (int j = 0; j < 8; ++j) v[j] = (__bf16)0.f;
        }
        *(v8bf*)&Abuf[s * 8] = v;
    }
    __syncthreads();

    f32x16 acc;
    #pragma unroll
    for (int j = 0; j < 16; ++j) acc[j] = 0.f;

    const __bf16* wf_g = wf + (long)((w * 16 + ht) * 32) * 64 * 8;
    #pragma unroll 4
    for (int k16 = 0; k16 < 32; ++k16) {
        const v8bf a = *(const v8bf*)&Abuf[(k16 * 64 + lane) * 8];
        const v8bf b = *(const v8bf*)&wf_g[(k16 * 64 + lane) * 8];
        acc = __builtin_amdgcn_mfma_f32_32x32x16_bf16(a, b, acc, 0, 0, 0);
    }
    __syncthreads();

    #pragma unroll
    for (int it = 0; it < 8; ++it) {
        const int s   = it * 256 + tid;
        const int k16 = s >> 6, ln = s & 63;
        const int r   = ln & 31;
        const int k   = k16 * 16 + ((ln >> 5) << 3);
        *(v8bf*)&Abuf[s * 8] = *(const v8bf*)&hbf_in[(long)(mt * 32 + r) * 512 + k];
    }
    __syncthreads();

    const __bf16* wf_h = wf + WHALF + (long)((w * 16 + ht) * 32) * 64 * 8;
    #pragma unroll 4
    for (int k16 = 0; k16 < 32; ++k16) {
        const v8bf a = *(const v8bf*)&Abuf[(k16 * 64 + lane) * 8];
        const v8bf b = *(const v8bf*)&wf_h[(k16 * 64 + lane) * 8];
        acc = __builtin_amdgcn_mfma_f32_32x32x16_bf16(a, b, acc, 0, 0, 0);
    }

    const int col  = lane & 31;
    const int half = lane >> 5;
    const int gidx = w * 512 + ht * 32 + col;
    const float bias = bih[gidx] + bhh[gidx];
    #pragma unroll
    for (int r = 0; r < 16; ++r) {
        const int m = (r & 3) + 8 * (r >> 2) + 4 * half;
        Gs[w][m][col] = acc[r] + bias;
    }
    __syncthreads();

    {
        const int m  = tid >> 3;
        const int nb = (tid & 7) << 2;
        const int b  = mt * 32 + m;
        if (b < BATCH) {
            const float4 gi = *(const float4*)&Gs[0][m][nb];
            const float4 gf = *(const float4*)&Gs[1][m][nb];
            const float4 gg = *(const float4*)&Gs[2][m][nb];
            const float4 go = *(const float4*)&Gs[3][m][nb];
            const long cix = (long)b * 512 + ht * 32 + nb;
            float4 cvv = *(const float4*)&c[cix];
            float4 hv;
            {
                const float i0 = sigm_(gi.x), f0 = sigm_(gf.x), g0 = tanh_(gg.x), o0 = sigm_(go.x);
                cvv.x = f0 * cvv.x + i0 * g0; hv.x = o0 * tanh_(cvv.x);
                const float i1 = sigm_(gi.y), f1 = sigm_(gf.y), g1 = tanh_(gg.y), o1 = sigm_(go.y);
                cvv.y = f1 * cvv.y + i1 * g1; hv.y = o1 * tanh_(cvv.y);
                const float i2 = sigm_(gi.z), f2 = sigm_(gf.z), g2 = tanh_(gg.z), o2 = sigm_(go.z);
                cvv.z = f2 * cvv.z + i2 * g2; hv.z = o2 * tanh_(cvv.z);
                const float i3 = sigm_(gi.w), f3 = sigm_(gf.w), g3 = tanh_(gg.w), o3 = sigm_(go.w);
                cvv.w = f3 * cvv.w + i3 * g3; hv.w = o3 * tanh_(cvv.w);
            }
            *(float4*)&c[cix] = cvv;
            *(float4*)&h[cix] = hv;
            union { uint2 u; __bf16 b4[4]; } z;
            z.b4[0] = (__bf16)hv.x; z.b4[1] = (__bf16)hv.y;
            z.b4[2] = (__bf16)hv.z; z.b4[3] = (__bf16)hv.w;
            *(uint2*)&hbf_out[cix] = z.u;
        }
    }
}

__global__ __launch_bounds__(256) void fc_kernel(
    const float* __restrict__ h, const float* __restrict__ Wfc,
    const float* __restrict__ bfc, float* __restrict__ out, int t)
{
    const int b    = blockIdx.x;
    const int lane = threadIdx.x & 63;
    const int w    = threadIdx.x >> 6;

    const float* hb = h + (long)b * HIDDEN + lane * 8;
    const float4 h0 = *(const float4*)(hb);
    const float4 h1 = *(const float4*)(hb + 4);
    float* outb = out + (long)b * TSTEPS * OUTF + (long)t * OUTF;

    for (int oi = 0; oi < 25; ++oi) {
        const int o = w * 25 + oi;
        const float* wr = Wfc + (long)o * HIDDEN + lane * 8;
        const float4 w0 = *(const float4*)(wr);
        const float4 w1 = *(const float4*)(wr + 4);
        float p = h0.x * w0.x + h0.y * w0.y + h0.z * w0.z + h0.w * w0.w
                + h1.x * w1.x + h1.y * w1.y + h1.z * w1.z + h1.w * w1.w;
        #pragma unroll
        for (int s = 32; s > 0; s >>= 1) p += __shfl_xor(p, s, 64);
        if (lane == 0) outb[o] = sigm_(p + bfc[o]);
    }
}

extern "C" void kernel_launch(void* const* d_in, const int* in_sizes, int n_in,
                              void* d_out, int out_size, void* d_ws, size_t ws_size,
                              hipStream_t stream) {
    const float* x   = (const float*)d_in[0];
    const float* Wih = (const float*)d_in[1];
    const float* Whh = (const float*)d_in[2];
    const float* bih = (const float*)d_in[3];
    const float* bhh = (const float*)d_in[4];
    const float* Wfc = (const float*)d_in[5];
    const float* bfc = (const float*)d_in[6];
    float* out = (float*)d_out;

    // fast-path ws: [cnt 2KB][hf 257*512KB][wf 4MB][wfc 128KB][xbf 128MB opt]
    const size_t HF_BYTES  = (size_t)257 * (NSLOT * 2);              // 134,742,016
    const size_t FAST_WS   = 2048 + HF_BYTES + (size_t)2 * WHALF * 2 + 131072; // 139,069,440
    const size_t XBF_WS    = FAST_WS + (size_t)TSTEPS * NSLOT * 2;   // 273,287,168

    if (ws_size >= FAST_WS) {
        char* p = (char*)d_ws;
        unsigned* cnt  = (unsigned*)p;
        __bf16*   hf   = (__bf16*)(p + 2048);
        __bf16*   wf   = (__bf16*)(p + 2048 + HF_BYTES);
        __bf16*   wfcf = wf + 2 * WHALF;
        __bf16*   xbf  = (__bf16*)(p + FAST_WS);
        const int use_xbf = (ws_size >= XBF_WS) ? 1 : 0;

        // zero barrier counters + hf slot 0 (h_{-1} = 0)
        hipMemsetAsync(d_ws, 0, 2048 + (size_t)NSLOT * 2, stream);

        convert_w<<<1024, 256, 0, stream>>>(Wih, Whh, wf);
        convert_wfc<<<32, 256, 0, stream>>>(Wfc, wfcf);
        if (use_xbf) convert_x<<<32768, 256, 0, stream>>>(x, xbf);

        lstm_persist<<<GRIDP, 256, 0, stream>>>(x, wf, bih, bhh, hf, xbf, cnt, use_xbf);
        fc_mfma<<<dim3(TSTEPS, 16), 256, 0, stream>>>(hf, wfcf, bfc, out);
    } else {
        // fallback ws: [c fp32 1MB][hbfA 0.5MB][hbfB 0.5MB][h fp32 1MB][wf bf16 4MB]
        float*  c    = (float*)d_ws;
        __bf16* hbfA = (__bf16*)(c + MPAD * HIDDEN);
        __bf16* hbfB = hbfA + MPAD * HIDDEN;
        float*  h    = (float*)(hbfB + MPAD * HIDDEN);
        __bf16* wf   = (__bf16*)(h + MPAD * HIDDEN);

        hipMemsetAsync(d_ws, 0, (size_t)MPAD * HIDDEN * 4 + (size_t)2 * MPAD * HIDDEN * 2, stream);
        convert_w<<<1024, 256, 0, stream>>>(Wih, Whh, wf);

        const dim3 ggrid(16, 16);
        for (int t = 0; t < TSTEPS; ++t) {
            const __bf16* hin  = (t & 1) ? hbfB : hbfA;
            __bf16*       hout = (t & 1) ? hbfA : hbfB;
            gates_cell<<<ggrid, 256, 0, stream>>>(x, hin, wf, bih, bhh, c, h, hout, t);
            fc_kernel<<<BATCH, 256, 0, stream>>>(h, Wfc, bfc, out, t);
        }
    }
}

// Round 3
// 3160.674 us; speedup vs baseline: 2.3533x; 1.8635x over previous
//
#include <hip/hip_runtime.h>
#include <hip/hip_bf16.h>
#include <math.h>

#define EMBED  512
#define HIDDEN 512
#define NGATE  2048
#define OUTF   100
#define BATCH  500
#define TSTEPS 256
#define XROW   (TSTEPS * EMBED)     // 131072 floats per batch row of x
#define MPAD   512                  // batch padded to 512
#define WHALF  1048576              // frag elems per W matrix: 64nt * 32k16 * 64lane * 8
#define NSLOT  262144               // bf16 elems per h/x time-slot: 16mt * 2048 * 8
#define SLOTB  ((size_t)NSLOT * 2 + 4096)   // hf slot stride in bytes (4KB pad: prefetch guard)
#define GRIDP  256                  // persistent grid: 16 ht x 16 mt

typedef __bf16 v8bf   __attribute__((ext_vector_type(8)));
typedef float  f32x16 __attribute__((ext_vector_type(16)));

__device__ __forceinline__ float sigm_(float v) { return 1.f / (1.f + __expf(-v)); }
__device__ __forceinline__ float tanh_(float v) { return 1.f - 2.f / (__expf(2.f * v) + 1.f); }

// async global->LDS, 16B per lane; LDS dest is wave-uniform base + lane*16.
__device__ __forceinline__ void dma16(const __bf16* g, __bf16* l) {
    __builtin_amdgcn_global_load_lds(
        (const __attribute__((address_space(1))) unsigned int*)g,
        (__attribute__((address_space(3))) unsigned int*)l, 16, 0, 0);
}

// write-through 8B store: goes to the device coherence point (L3), no dirty L2 line.
__device__ __forceinline__ void store8_wt(void* p, unsigned long long v) {
    asm volatile("global_store_dwordx2 %0, %1, off sc0 sc1" :: "v"(p), "v"(v) : "memory");
}
__device__ __forceinline__ void drain_vm() {
    asm volatile("s_waitcnt vmcnt(0)" ::: "memory");
}

// ---------------------------------------------------------------------------
// One-time: W_ih / W_hh (fp32 (2048,512)) -> bf16 MFMA B-fragment order:
//   wf[which][nt][k16][lane][8], row = nt*32+(lane&31), k = k16*16+(lane>>5)*8+slot
// ---------------------------------------------------------------------------
__global__ __launch_bounds__(256) void convert_w(
    const float* __restrict__ Wih, const float* __restrict__ Whh,
    __bf16* __restrict__ wf)
{
    const int idx   = blockIdx.x * 256 + threadIdx.x;   // 0..262143
    const int which = idx >> 17;
    const int s     = idx & 131071;                     // (nt*32 + k16)*64 + lane
    const int lane  = s & 63;
    const int k16   = (s >> 6) & 31;
    const int nt    = s >> 11;
    const int row   = nt * 32 + (lane & 31);
    const int k     = k16 * 16 + ((lane >> 5) << 3);
    const float* W  = which ? Whh : Wih;
    const float* p  = W + (long)row * 512 + k;
    const float4 f0 = *(const float4*)p;
    const float4 f1 = *(const float4*)(p + 4);
    v8bf v;
    v[0] = (__bf16)f0.x; v[1] = (__bf16)f0.y; v[2] = (__bf16)f0.z; v[3] = (__bf16)f0.w;
    v[4] = (__bf16)f1.x; v[5] = (__bf16)f1.y; v[6] = (__bf16)f1.z; v[7] = (__bf16)f1.w;
    *(v8bf*)&wf[(long)which * WHALF + (long)s * 8] = v;
}

// W_fc (100,512) fp32 -> bf16 frags, N padded to 128 (rows >=100 zeroed).
__global__ __launch_bounds__(256) void convert_wfc(
    const float* __restrict__ Wfc, __bf16* __restrict__ wfcf)
{
    const int s    = blockIdx.x * 256 + threadIdx.x;    // 0..8191
    const int lane = s & 63;
    const int k16  = (s >> 6) & 31;
    const int nt   = s >> 11;                           // 0..3
    const int row  = nt * 32 + (lane & 31);
    const int k    = k16 * 16 + ((lane >> 5) << 3);
    v8bf v;
    if (row < OUTF) {
        const float* p  = Wfc + (long)row * HIDDEN + k;
        const float4 f0 = *(const float4*)p;
        const float4 f1 = *(const float4*)(p + 4);
        v[0] = (__bf16)f0.x; v[1] = (__bf16)f0.y; v[2] = (__bf16)f0.z; v[3] = (__bf16)f0.w;
        v[4] = (__bf16)f1.x; v[5] = (__bf16)f1.y; v[6] = (__bf16)f1.z; v[7] = (__bf16)f1.w;
    } else {
        #pragma unroll
        for (int j = 0; j < 8; ++j) v[j] = (__bf16)0.f;
    }
    *(v8bf*)&wfcf[(size_t)s * 8] = v;
}

// Optional one-time: x (fp32) -> bf16 A-fragment order per (t, mt) slot.
__global__ __launch_bounds__(256) void convert_x(
    const float* __restrict__ x, __bf16* __restrict__ xbf)
{
    const int idx = blockIdx.x * 256 + threadIdx.x;     // 0 .. 256*16*2048-1
    const int ts  = idx >> 15;
    const int rem = idx & 32767;
    const int mt  = rem >> 11;
    const int s   = rem & 2047;
    const int ln  = s & 63;
    const int k16 = s >> 6;
    const int r   = ln & 31;
    const int b   = mt * 32 + r;
    const int k   = k16 * 16 + ((ln >> 5) << 3);
    v8bf v;
    if (b < BATCH) {
        const float* p  = x + (size_t)b * XROW + (size_t)ts * EMBED + k;
        const float4 f0 = *(const float4*)p;
        const float4 f1 = *(const float4*)(p + 4);
        v[0] = (__bf16)f0.x; v[1] = (__bf16)f0.y; v[2] = (__bf16)f0.z; v[3] = (__bf16)f0.w;
        v[4] = (__bf16)f1.x; v[5] = (__bf16)f1.y; v[6] = (__bf16)f1.z; v[7] = (__bf16)f1.w;
    } else {
        #pragma unroll
        for (int j = 0; j < 8; ++j) v[j] = (__bf16)0.f;
    }
    *(v8bf*)&xbf[(size_t)idx * 8] = v;
}

// ---------------------------------------------------------------------------
// Persistent LSTM, fence-free, producer/consumer wave split.
// Grid 256 = (ht = bid>>4) x (mt = bid&15); block = 8 waves (512 thr):
//   waves 0-3 (rec): h-part MFMAs (W_hh in regs), cell update, hf publish.
//   waves 4-7 (x):   xacc(t+1) = x(t+1)·W_ih, handed over via LDS dbuf.
// h exchange: write-through stores (sc0 sc1) -> vmcnt drain -> relaxed agent
// atomic add; readers poll relaxed agent atomic load + plain cached DMA.
// No fences in the loop -> L2 stays warm for W/x across steps.
// ---------------------------------------------------------------------------
__global__ __launch_bounds__(512, 2) void lstm_persist(
    const float*  __restrict__ x,
    const __bf16* __restrict__ wf,
    const float*  __restrict__ bih, const float* __restrict__ bhh,
    char* __restrict__ hfb,           // 257 slots of SLOTB bytes; slot t = h_{t-1}
    const __bf16* __restrict__ xbf,   // optional frag-ordered x
    unsigned* __restrict__ cnt,       // 16 groups * 32 u32 (128B stride)
    int use_xbf)
{
    __shared__ __align__(16) __bf16 Habuf[2048 * 8];   // 32 KB h fragment tile
    __shared__ __align__(16) __bf16 Xabuf[2048 * 8];   // 32 KB x fragment tile
    __shared__ __align__(16) float  Xacc[2][4][16][64];// 32 KB xacc handoff (dbuf)
    __shared__ __align__(16) float  Gs[4][32][36];     // gate exchange

    const int tid  = threadIdx.x;
    const int lane = tid & 63;
    const int w8   = tid >> 6;             // 0..7
    const bool isrec = (w8 < 4);
    const int w    = w8 & 3;               // gate index within group
    const int bid  = blockIdx.x;
    const int mt   = bid & 15;
    const int ht   = bid >> 4;
    const int t255 = tid & 255;

    unsigned* cnt_mt = cnt + mt * 32;

    const int col  = lane & 31;
    const int half = lane >> 5;
    const int gidx = w * 512 + ht * 32 + col;
    const float bias = bih[gidx] + bhh[gidx];

    const int cm  = t255 >> 3;             // batch row in tile (rec threads)
    const int cnb = (t255 & 7) << 2;       // hidden col base (within ht tile)
    const int hid = ht * 32 + cnb;
    const size_t hwoff = ((size_t)mt * 2048 + (size_t)(hid >> 4) * 64
                          + (size_t)(cm + (((hid >> 3) & 1) << 5))) * 8 + (hid & 7);

    const __bf16* wfi = wf + (size_t)(w * 16 + ht) * 16384;          // W_ih frags (gate w)
    const __bf16* wfh = wf + WHALF + (size_t)(w * 16 + ht) * 16384;  // W_hh frags

    // rec waves: preload W_hh fragments into registers (128 VGPR)
    v8bf whh[32];
    if (isrec) {
        #pragma unroll
        for (int k16 = 0; k16 < 32; ++k16)
            whh[k16] = *(const v8bf*)&wfh[k16 * 512 + lane * 8];
    }

    float4 cv = make_float4(0.f, 0.f, 0.f, 0.f);

    // ---- prologue: x waves compute xacc(0) -> Xacc[0]
    if (!isrec) {
        if (use_xbf) {
            const __bf16* xsrc = xbf + (size_t)mt * 16384;           // ts = 0
            #pragma unroll
            for (int it = 0; it < 8; ++it) {
                const int sb = it * 256 + w * 64;
                dma16(xsrc + (size_t)(sb + lane) * 8, &Xabuf[sb * 8]);
            }
        } else {
            #pragma unroll
            for (int it = 0; it < 8; ++it) {
                const int s   = it * 256 + t255;
                const int k16 = s >> 6, ln = s & 63;
                const int r   = ln & 31;
                const int b   = mt * 32 + r;
                const int k   = k16 * 16 + ((ln >> 5) << 3);
                v8bf v;
                if (b < BATCH) {
                    const float* p  = x + (size_t)b * XROW + k;      // ts = 0
                    const float4 f0 = *(const float4*)p;
                    const float4 f1 = *(const float4*)(p + 4);
                    v[0] = (__bf16)f0.x; v[1] = (__bf16)f0.y; v[2] = (__bf16)f0.z; v[3] = (__bf16)f0.w;
                    v[4] = (__bf16)f1.x; v[5] = (__bf16)f1.y; v[6] = (__bf16)f1.z; v[7] = (__bf16)f1.w;
                } else {
                    #pragma unroll
                    for (int j = 0; j < 8; ++j) v[j] = (__bf16)0.f;
                }
                *(v8bf*)&Xabuf[s * 8] = v;
            }
        }
    }
    __syncthreads();
    if (!isrec) {
        f32x16 xa;
        #pragma unroll
        for (int j = 0; j < 16; ++j) xa[j] = 0.f;
        #pragma unroll
        for (int k16 = 0; k16 < 32; ++k16) {
            const v8bf a = *(const v8bf*)&Xabuf[(k16 * 64 + lane) * 8];
            const v8bf b = *(const v8bf*)&wfi[k16 * 512 + lane * 8];
            xa = __builtin_amdgcn_mfma_f32_32x32x16_bf16(a, b, xa, 0, 0, 0);
        }
        #pragma unroll
        for (int r = 0; r < 16; ++r) Xacc[0][w][r][lane] = xa[r];
    }
    __syncthreads();

    #pragma unroll 1
    for (int t = 0; t < TSTEPS; ++t) {
        // ---- A: rec tid0 polls peers; x waves stage x(t+1)
        if (tid == 0 && t > 0) {
            const unsigned target = 16u * (unsigned)t;
            unsigned iters = 0;
            while (__hip_atomic_load(cnt_mt, __ATOMIC_RELAXED, __HIP_MEMORY_SCOPE_AGENT) < target) {
                __builtin_amdgcn_s_sleep(1);
                if (++iters > 100000000u) break;   // escape hatch: never hang
            }
        }
        if (!isrec && t + 1 < TSTEPS) {
            const int ts = t + 1;
            if (use_xbf) {
                const __bf16* xsrc = xbf + (size_t)ts * NSLOT + (size_t)mt * 16384;
                #pragma unroll
                for (int it = 0; it < 8; ++it) {
                    const int sb = it * 256 + w * 64;
                    dma16(xsrc + (size_t)(sb + lane) * 8, &Xabuf[sb * 8]);
                }
            } else {
                #pragma unroll
                for (int it = 0; it < 8; ++it) {
                    const int s   = it * 256 + t255;
                    const int k16 = s >> 6, ln = s & 63;
                    const int r   = ln & 31;
                    const int b   = mt * 32 + r;
                    const int k   = k16 * 16 + ((ln >> 5) << 3);
                    v8bf v;
                    if (b < BATCH) {
                        const float* p  = x + (size_t)b * XROW + (size_t)ts * EMBED + k;
                        const float4 f0 = *(const float4*)p;
                        const float4 f1 = *(const float4*)(p + 4);
                        v[0] = (__bf16)f0.x; v[1] = (__bf16)f0.y; v[2] = (__bf16)f0.z; v[3] = (__bf16)f0.w;
                        v[4] = (__bf16)f1.x; v[5] = (__bf16)f1.y; v[6] = (__bf16)f1.z; v[7] = (__bf16)f1.w;
                    } else {
                        #pragma unroll
                        for (int j = 0; j < 8; ++j) v[j] = (__bf16)0.f;
                    }
                    *(v8bf*)&Xabuf[s * 8] = v;
                }
            }
        }
        __syncthreads();                                  // B1: h_{t-1} ready; Xabuf staged

        if (isrec) {
            // DMA h_{t-1} frags (plain cached; lines never stale on this XCD)
            const __bf16* hsrc = (const __bf16*)(hfb + (size_t)t * SLOTB) + (size_t)mt * 16384;
            #pragma unroll
            for (int it = 0; it < 8; ++it) {
                const int sb = it * 256 + w * 64;
                dma16(hsrc + (size_t)(sb + lane) * 8, &Habuf[sb * 8]);
            }
        } else if (t + 1 < TSTEPS) {
            // xacc(t+1) concurrent with rec's h work
            f32x16 xa;
            #pragma unroll
            for (int j = 0; j < 16; ++j) xa[j] = 0.f;
            #pragma unroll
            for (int k16 = 0; k16 < 32; ++k16) {
                const v8bf a = *(const v8bf*)&Xabuf[(k16 * 64 + lane) * 8];
                const v8bf b = *(const v8bf*)&wfi[k16 * 512 + lane * 8];
                xa = __builtin_amdgcn_mfma_f32_32x32x16_bf16(a, b, xa, 0, 0, 0);
            }
            const int nb = (t + 1) & 1;
            #pragma unroll
            for (int r = 0; r < 16; ++r) Xacc[nb][w][r][lane] = xa[r];
        }
        __syncthreads();                                  // B2: Habuf ready; xacc(t+1) stored

        if (isrec) {
            f32x16 acc;
            const int cb = t & 1;
            #pragma unroll
            for (int r = 0; r < 16; ++r) acc[r] = Xacc[cb][w][r][lane];
            #pragma unroll
            for (int k16 = 0; k16 < 32; ++k16) {
                const v8bf a = *(const v8bf*)&Habuf[(k16 * 64 + lane) * 8];
                acc = __builtin_amdgcn_mfma_f32_32x32x16_bf16(a, whh[k16], acc, 0, 0, 0);
            }
            #pragma unroll
            for (int r = 0; r < 16; ++r) {
                const int mr = (r & 3) + 8 * (r >> 2) + 4 * half;
                Gs[w][mr][col] = acc[r] + bias;
            }
        }
        __syncthreads();                                  // B3: Gs ready

        if (isrec) {
            const float4 gi = *(const float4*)&Gs[0][cm][cnb];
            const float4 gf = *(const float4*)&Gs[1][cm][cnb];
            const float4 gg = *(const float4*)&Gs[2][cm][cnb];
            const float4 go = *(const float4*)&Gs[3][cm][cnb];
            float4 hv;
            const float i0 = sigm_(gi.x), f0 = sigm_(gf.x), g0 = tanh_(gg.x), o0 = sigm_(go.x);
            cv.x = f0 * cv.x + i0 * g0; hv.x = o0 * tanh_(cv.x);
            const float i1 = sigm_(gi.y), f1 = sigm_(gf.y), g1 = tanh_(gg.y), o1 = sigm_(go.y);
            cv.y = f1 * cv.y + i1 * g1; hv.y = o1 * tanh_(cv.y);
            const float i2 = sigm_(gi.z), f2 = sigm_(gf.z), g2 = tanh_(gg.z), o2 = sigm_(go.z);
            cv.z = f2 * cv.z + i2 * g2; hv.z = o2 * tanh_(cv.z);
            const float i3 = sigm_(gi.w), f3 = sigm_(gf.w), g3 = tanh_(gg.w), o3 = sigm_(go.w);
            cv.w = f3 * cv.w + i3 * g3; hv.w = o3 * tanh_(cv.w);
            union { unsigned long long u; __bf16 b4[4]; } z;
            z.b4[0] = (__bf16)hv.x; z.b4[1] = (__bf16)hv.y;
            z.b4[2] = (__bf16)hv.z; z.b4[3] = (__bf16)hv.w;
            store8_wt(hfb + (size_t)(t + 1) * SLOTB + hwoff * 2, z.u);
            drain_vm();                                   // write-through acked at L3
        }
        __syncthreads();                                  // B4: all rec stores drained
        if (tid == 0)
            __hip_atomic_fetch_add(cnt_mt, 1u, __ATOMIC_RELAXED, __HIP_MEMORY_SCOPE_AGENT);
    }
}

// ---------------------------------------------------------------------------
// Deferred FC head: one launch for all (b,t). out = sigmoid(h @ Wfc^T + bfc).
// Block (t, mt): A = hf slot t+1 (frag order, DMA), B = wfcf (N padded 128).
// ---------------------------------------------------------------------------
__global__ __launch_bounds__(256) void fc_mfma(
    const char* __restrict__ hfb, const __bf16* __restrict__ wfcf,
    const float* __restrict__ bfc, float* __restrict__ out)
{
    __shared__ __align__(16) __bf16 Abuf[2048 * 8];
    __shared__ __align__(16) float  Fs[32][132];

    const int tid  = threadIdx.x;
    const int lane = tid & 63;
    const int w    = tid >> 6;
    const int t    = blockIdx.x;
    const int mt   = blockIdx.y;

    const __bf16* hsrc = (const __bf16*)(hfb + (size_t)(t + 1) * SLOTB) + (size_t)mt * 16384;
    #pragma unroll
    for (int it = 0; it < 8; ++it) {
        const int sb = it * 256 + w * 64;
        dma16(hsrc + (size_t)(sb + lane) * 8, &Abuf[sb * 8]);
    }
    __syncthreads();

    f32x16 acc;
    #pragma unroll
    for (int j = 0; j < 16; ++j) acc[j] = 0.f;
    const __bf16* wfw = wfcf + (size_t)w * 16384;
    #pragma unroll
    for (int k16 = 0; k16 < 32; ++k16) {
        const v8bf a = *(const v8bf*)&Abuf[(k16 * 64 + lane) * 8];
        const v8bf b = *(const v8bf*)&wfw[k16 * 512 + lane * 8];
        acc = __builtin_amdgcn_mfma_f32_32x32x16_bf16(a, b, acc, 0, 0, 0);
    }

    const int col = lane & 31, half = lane >> 5;
    #pragma unroll
    for (int r = 0; r < 16; ++r) {
        const int mr = (r & 3) + 8 * (r >> 2) + 4 * half;
        Fs[mr][w * 32 + col] = acc[r];
    }
    __syncthreads();

    const int mr = tid >> 3;
    const int b  = mt * 32 + mr;
    if (b < BATCH) {
        const int c0 = (tid & 7) * 16;
        float* ob = out + ((size_t)b * TSTEPS + t) * OUTF;
        #pragma unroll
        for (int j = 0; j < 4; ++j) {
            const int o = c0 + j * 4;
            if (o < OUTF) {
                const float4 v  = *(const float4*)&Fs[mr][o];
                const float4 bv = *(const float4*)&bfc[o];
                float4 r4;
                r4.x = sigm_(v.x + bv.x); r4.y = sigm_(v.y + bv.y);
                r4.z = sigm_(v.z + bv.z); r4.w = sigm_(v.w + bv.w);
                *(float4*)&ob[o] = r4;
            }
        }
    }
}

// ===========================================================================
// Fallback path (verified round-0 structure): per-step gates_cell + fc_kernel.
// Used when ws_size cannot hold the 257-slot hf ring.
// ===========================================================================
__global__ __launch_bounds__(256) void gates_cell(
    const float*  __restrict__ x,
    const __bf16* __restrict__ hbf_in,
    const __bf16* __restrict__ wf,
    const float*  __restrict__ bih, const float* __restrict__ bhh,
    float* __restrict__ c,
    float* __restrict__ h,
    __bf16* __restrict__ hbf_out,
    int t)
{
    __shared__ __bf16 Abuf[32 * 64 * 8];
    __shared__ float  Gs[4][32][36];

    const int tid  = threadIdx.x;
    const int lane = tid & 63;
    const int w    = tid >> 6;
    const int ht   = blockIdx.x;
    const int mt   = blockIdx.y;

    #pragma unroll
    for (int it = 0; it < 8; ++it) {
        const int s   = it * 256 + tid;
        const int k16 = s >> 6, ln = s & 63;
        const int r   = ln & 31;
        const int b   = mt * 32 + r;
        const int k   = k16 * 16 + ((ln >> 5) << 3);
        v8bf v;
        if (b < BATCH) {
            const float* p = x + (long)b * XROW + (long)t * EMBED + k;
            const float4 f0 = *(const float4*)p;
            const float4 f1 = *(const float4*)(p + 4);
            v[0] = (__bf16)f0.x; v[1] = (__bf16)f0.y; v[2] = (__bf16)f0.z; v[3] = (__bf16)f0.w;
            v[4] = (__bf16)f1.x; v[5] = (__bf16)f1.y; v[6] = (__bf16)f1.z; v[7] = (__bf16)f1.w;
        } else {
            #pragma unroll
            for (int j = 0; j < 8; ++j) v[j] = (__bf16)0.f;
        }
        *(v8bf*)&Abuf[s * 8] = v;
    }
    __syncthreads();

    f32x16 acc;
    #pragma unroll
    for (int j = 0; j < 16; ++j) acc[j] = 0.f;

    const __bf16* wf_g = wf + (long)((w * 16 + ht) * 32) * 64 * 8;
    #pragma unroll 4
    for (int k16 = 0; k16 < 32; ++k16) {
        const v8bf a = *(const v8bf*)&Abuf[(k16 * 64 + lane) * 8];
        const v8bf b = *(const v8bf*)&wf_g[(k16 * 64 + lane) * 8];
        acc = __builtin_amdgcn_mfma_f32_32x32x16_bf16(a, b, acc, 0, 0, 0);
    }
    __syncthreads();

    #pragma unroll
    for (int it = 0; it < 8; ++it) {
        const int s   = it * 256 + tid;
        const int k16 = s >> 6, ln = s & 63;
        const int r   = ln & 31;
        const int k   = k16 * 16 + ((ln >> 5) << 3);
        *(v8bf*)&Abuf[s * 8] = *(const v8bf*)&hbf_in[(long)(mt * 32 + r) * 512 + k];
    }
    __syncthreads();

    const __bf16* wf_h = wf + WHALF + (long)((w * 16 + ht) * 32) * 64 * 8;
    #pragma unroll 4
    for (int k16 = 0; k16 < 32; ++k16) {
        const v8bf a = *(const v8bf*)&Abuf[(k16 * 64 + lane) * 8];
        const v8bf b = *(const v8bf*)&wf_h[(k16 * 64 + lane) * 8];
        acc = __builtin_amdgcn_mfma_f32_32x32x16_bf16(a, b, acc, 0, 0, 0);
    }

    const int col  = lane & 31;
    const int half = lane >> 5;
    const int gidx = w * 512 + ht * 32 + col;
    const float bias = bih[gidx] + bhh[gidx];
    #pragma unroll
    for (int r = 0; r < 16; ++r) {
        const int m = (r & 3) + 8 * (r >> 2) + 4 * half;
        Gs[w][m][col] = acc[r] + bias;
    }
    __syncthreads();

    {
        const int m  = tid >> 3;
        const int nb = (tid & 7) << 2;
        const int b  = mt * 32 + m;
        if (b < BATCH) {
            const float4 gi = *(const float4*)&Gs[0][m][nb];
            const float4 gf = *(const float4*)&Gs[1][m][nb];
            const float4 gg = *(const float4*)&Gs[2][m][nb];
            const float4 go = *(const float4*)&Gs[3][m][nb];
            const long cix = (long)b * 512 + ht * 32 + nb;
            float4 cvv = *(const float4*)&c[cix];
            float4 hv;
            {
                const float i0 = sigm_(gi.x), f0 = sigm_(gf.x), g0 = tanh_(gg.x), o0 = sigm_(go.x);
                cvv.x = f0 * cvv.x + i0 * g0; hv.x = o0 * tanh_(cvv.x);
                const float i1 = sigm_(gi.y), f1 = sigm_(gf.y), g1 = tanh_(gg.y), o1 = sigm_(go.y);
                cvv.y = f1 * cvv.y + i1 * g1; hv.y = o1 * tanh_(cvv.y);
                const float i2 = sigm_(gi.z), f2 = sigm_(gf.z), g2 = tanh_(gg.z), o2 = sigm_(go.z);
                cvv.z = f2 * cvv.z + i2 * g2; hv.z = o2 * tanh_(cvv.z);
                const float i3 = sigm_(gi.w), f3 = sigm_(gf.w), g3 = tanh_(gg.w), o3 = sigm_(go.w);
                cvv.w = f3 * cvv.w + i3 * g3; hv.w = o3 * tanh_(cvv.w);
            }
            *(float4*)&c[cix] = cvv;
            *(float4*)&h[cix] = hv;
            union { uint2 u; __bf16 b4[4]; } z;
            z.b4[0] = (__bf16)hv.x; z.b4[1] = (__bf16)hv.y;
            z.b4[2] = (__bf16)hv.z; z.b4[3] = (__bf16)hv.w;
            *(uint2*)&hbf_out[cix] = z.u;
        }
    }
}

__global__ __launch_bounds__(256) void fc_kernel(
    const float* __restrict__ h, const float* __restrict__ Wfc,
    const float* __restrict__ bfc, float* __restrict__ out, int t)
{
    const int b    = blockIdx.x;
    const int lane = threadIdx.x & 63;
    const int w    = threadIdx.x >> 6;

    const float* hb = h + (long)b * HIDDEN + lane * 8;
    const float4 h0 = *(const float4*)(hb);
    const float4 h1 = *(const float4*)(hb + 4);
    float* outb = out + (long)b * TSTEPS * OUTF + (long)t * OUTF;

    for (int oi = 0; oi < 25; ++oi) {
        const int o = w * 25 + oi;
        const float* wr = Wfc + (long)o * HIDDEN + lane * 8;
        const float4 w0 = *(const float4*)(wr);
        const float4 w1 = *(const float4*)(wr + 4);
        float p = h0.x * w0.x + h0.y * w0.y + h0.z * w0.z + h0.w * w0.w
                + h1.x * w1.x + h1.y * w1.y + h1.z * w1.z + h1.w * w1.w;
        #pragma unroll
        for (int s = 32; s > 0; s >>= 1) p += __shfl_xor(p, s, 64);
        if (lane == 0) outb[o] = sigm_(p + bfc[o]);
    }
}

extern "C" void kernel_launch(void* const* d_in, const int* in_sizes, int n_in,
                              void* d_out, int out_size, void* d_ws, size_t ws_size,
                              hipStream_t stream) {
    const float* x   = (const float*)d_in[0];
    const float* Wih = (const float*)d_in[1];
    const float* Whh = (const float*)d_in[2];
    const float* bih = (const float*)d_in[3];
    const float* bhh = (const float*)d_in[4];
    const float* Wfc = (const float*)d_in[5];
    const float* bfc = (const float*)d_in[6];
    float* out = (float*)d_out;

    // fast-path ws: [cnt 2KB][hf 257*SLOTB][wf 4MB][wfc 128KB][xbf 128MB opt]
    const size_t HF_BYTES = (size_t)257 * SLOTB;                        // 135,794,688
    const size_t FAST_WS  = 2048 + HF_BYTES + (size_t)4 * WHALF + 131072;
    const size_t XBF_WS   = FAST_WS + (size_t)TSTEPS * NSLOT * 2;

    if (ws_size >= FAST_WS) {
        char* p = (char*)d_ws;
        unsigned* cnt  = (unsigned*)p;
        char*     hfb  = p + 2048;
        __bf16*   wf   = (__bf16*)(p + 2048 + HF_BYTES);
        __bf16*   wfcf = wf + 2 * WHALF;
        __bf16*   xbf  = (__bf16*)(p + FAST_WS);
        const int use_xbf = (ws_size >= XBF_WS) ? 1 : 0;

        // zero barrier counters + hf slot 0 data region (h_{-1} = 0)
        hipMemsetAsync(d_ws, 0, 2048 + (size_t)NSLOT * 2, stream);

        convert_w<<<1024, 256, 0, stream>>>(Wih, Whh, wf);
        convert_wfc<<<32, 256, 0, stream>>>(Wfc, wfcf);
        if (use_xbf) convert_x<<<32768, 256, 0, stream>>>(x, xbf);

        lstm_persist<<<GRIDP, 512, 0, stream>>>(x, wf, bih, bhh, hfb, xbf, cnt, use_xbf);
        fc_mfma<<<dim3(TSTEPS, 16), 256, 0, stream>>>(hfb, wfcf, bfc, out);
    } else {
        // fallback ws: [c fp32 1MB][hbfA 0.5MB][hbfB 0.5MB][h fp32 1MB][wf bf16 4MB]
        float*  c    = (float*)d_ws;
        __bf16* hbfA = (__bf16*)(c + MPAD * HIDDEN);
        __bf16* hbfB = hbfA + MPAD * HIDDEN;
        float*  h    = (float*)(hbfB + MPAD * HIDDEN);
        __bf16* wf   = (__bf16*)(h + MPAD * HIDDEN);

        hipMemsetAsync(d_ws, 0, (size_t)MPAD * HIDDEN * 4 + (size_t)2 * MPAD * HIDDEN * 2, stream);
        convert_w<<<1024, 256, 0, stream>>>(Wih, Whh, wf);

        const dim3 ggrid(16, 16);
        for (int t = 0; t < TSTEPS; ++t) {
            const __bf16* hin  = (t & 1) ? hbfB : hbfA;
            __bf16*       hout = (t & 1) ? hbfA : hbfB;
            gates_cell<<<ggrid, 256, 0, stream>>>(x, hin, wf, bih, bhh, c, h, hout, t);
            fc_kernel<<<BATCH, 256, 0, stream>>>(h, Wfc, bfc, out, t);
        }
    }
}

// Round 5
// 1428.147 us; speedup vs baseline: 5.2083x; 2.2131x over previous
//
#include <hip/hip_runtime.h>
#include <hip/hip_bf16.h>
#include <math.h>

#define EMBED  512
#define HIDDEN 512
#define NGATE  2048
#define OUTF   100
#define BATCH  500
#define TSTEPS 256
#define XROW   (TSTEPS * EMBED)     // 131072 floats per batch row of x
#define MPAD   512                  // batch padded to 512
#define WHALF  1048576              // frag elems per W matrix: 64nt * 32k16 * 64lane * 8
#define NSLOT  262144               // bf16 elems per h/x time-slot: 16mt * 2048 * 8
#define SLOTB  ((size_t)NSLOT * 2 + 4096)   // hf slot stride in bytes (4KB pad: prefetch guard)
#define GRIDP  256                  // persistent grid: 16 ht x 16 mt

typedef __bf16 v8bf   __attribute__((ext_vector_type(8)));
typedef float  f32x16 __attribute__((ext_vector_type(16)));

__device__ __forceinline__ float sigm_(float v) { return 1.f / (1.f + __expf(-v)); }
__device__ __forceinline__ float tanh_(float v) { return 1.f - 2.f / (__expf(2.f * v) + 1.f); }

// async global->LDS, 16B per lane; LDS dest is wave-uniform base + lane*16.
__device__ __forceinline__ void dma16(const __bf16* g, __bf16* l) {
    __builtin_amdgcn_global_load_lds(
        (const __attribute__((address_space(1))) unsigned int*)g,
        (__attribute__((address_space(3))) unsigned int*)l, 16, 0, 0);
}

// write-through 8B store: goes to the device coherence point, no dirty L2 line.
__device__ __forceinline__ void store8_wt(void* p, unsigned long long v) {
    asm volatile("global_store_dwordx2 %0, %1, off sc0 sc1" :: "v"(p), "v"(v) : "memory");
}
__device__ __forceinline__ void drain_vm() {
    asm volatile("s_waitcnt vmcnt(0)" ::: "memory");
}

// ---------------------------------------------------------------------------
// One-time: W_ih / W_hh (fp32 (2048,512)) -> bf16 MFMA B-fragment order:
//   wf[which][nt][k16][lane][8], row = nt*32+(lane&31), k = k16*16+(lane>>5)*8+slot
// ---------------------------------------------------------------------------
__global__ __launch_bounds__(256) void convert_w(
    const float* __restrict__ Wih, const float* __restrict__ Whh,
    __bf16* __restrict__ wf)
{
    const int idx   = blockIdx.x * 256 + threadIdx.x;   // 0..262143
    const int which = idx >> 17;
    const int s     = idx & 131071;                     // (nt*32 + k16)*64 + lane
    const int lane  = s & 63;
    const int k16   = (s >> 6) & 31;
    const int nt    = s >> 11;
    const int row   = nt * 32 + (lane & 31);
    const int k     = k16 * 16 + ((lane >> 5) << 3);
    const float* W  = which ? Whh : Wih;
    const float* p  = W + (long)row * 512 + k;
    const float4 f0 = *(const float4*)p;
    const float4 f1 = *(const float4*)(p + 4);
    v8bf v;
    v[0] = (__bf16)f0.x; v[1] = (__bf16)f0.y; v[2] = (__bf16)f0.z; v[3] = (__bf16)f0.w;
    v[4] = (__bf16)f1.x; v[5] = (__bf16)f1.y; v[6] = (__bf16)f1.z; v[7] = (__bf16)f1.w;
    *(v8bf*)&wf[(long)which * WHALF + (long)s * 8] = v;
}

// W_fc (100,512) fp32 -> bf16 frags, N padded to 128 (rows >=100 zeroed).
__global__ __launch_bounds__(256) void convert_wfc(
    const float* __restrict__ Wfc, __bf16* __restrict__ wfcf)
{
    const int s    = blockIdx.x * 256 + threadIdx.x;    // 0..8191
    const int lane = s & 63;
    const int k16  = (s >> 6) & 31;
    const int nt   = s >> 11;                           // 0..3
    const int row  = nt * 32 + (lane & 31);
    const int k    = k16 * 16 + ((lane >> 5) << 3);
    v8bf v;
    if (row < OUTF) {
        const float* p  = Wfc + (long)row * HIDDEN + k;
        const float4 f0 = *(const float4*)p;
        const float4 f1 = *(const float4*)(p + 4);
        v[0] = (__bf16)f0.x; v[1] = (__bf16)f0.y; v[2] = (__bf16)f0.z; v[3] = (__bf16)f0.w;
        v[4] = (__bf16)f1.x; v[5] = (__bf16)f1.y; v[6] = (__bf16)f1.z; v[7] = (__bf16)f1.w;
    } else {
        #pragma unroll
        for (int j = 0; j < 8; ++j) v[j] = (__bf16)0.f;
    }
    *(v8bf*)&wfcf[(size_t)s * 8] = v;
}

// Optional one-time: x (fp32) -> bf16 A-fragment order per (t, mt) slot.
__global__ __launch_bounds__(256) void convert_x(
    const float* __restrict__ x, __bf16* __restrict__ xbf)
{
    const int idx = blockIdx.x * 256 + threadIdx.x;     // 0 .. 256*16*2048-1
    const int ts  = idx >> 15;
    const int rem = idx & 32767;
    const int mt  = rem >> 11;
    const int s   = rem & 2047;
    const int ln  = s & 63;
    const int k16 = s >> 6;
    const int r   = ln & 31;
    const int b   = mt * 32 + r;
    const int k   = k16 * 16 + ((ln >> 5) << 3);
    v8bf v;
    if (b < BATCH) {
        const float* p  = x + (size_t)b * XROW + (size_t)ts * EMBED + k;
        const float4 f0 = *(const float4*)p;
        const float4 f1 = *(const float4*)(p + 4);
        v[0] = (__bf16)f0.x; v[1] = (__bf16)f0.y; v[2] = (__bf16)f0.z; v[3] = (__bf16)f0.w;
        v[4] = (__bf16)f1.x; v[5] = (__bf16)f1.y; v[6] = (__bf16)f1.z; v[7] = (__bf16)f1.w;
    } else {
        #pragma unroll
        for (int j = 0; j < 8; ++j) v[j] = (__bf16)0.f;
    }
    *(v8bf*)&xbf[(size_t)idx * 8] = v;
}

// ---------------------------------------------------------------------------
// Persistent LSTM, fence-free, producer/consumer wave split.
// Grid 256 = (ht = bid>>4) x (mt = bid&15); block = 8 waves (512 thr):
//   waves 0-3 (rec): h-part MFMAs (W_hh in regs), cell update, hf publish.
//   waves 4-7 (x):   xacc(t+1) = x(t+1)·W_ih (W_ih in regs), LDS-dbuf handoff.
// Both roles hold their 32 B-fragments in ONE register array wreg[32]
// (isrec ? W_hh : W_ih) -> no per-step W loads from L2/L3 on any path.
// h exchange: write-through stores (sc0 sc1) -> vmcnt drain -> relaxed agent
// atomic add; readers poll relaxed agent atomic load + plain cached DMA.
// ---------------------------------------------------------------------------
__global__ __launch_bounds__(512, 2) void lstm_persist(
    const float*  __restrict__ x,
    const __bf16* __restrict__ wf,
    const float*  __restrict__ bih, const float* __restrict__ bhh,
    char* __restrict__ hfb,           // 257 slots of SLOTB bytes; slot t = h_{t-1}
    const __bf16* __restrict__ xbf,   // optional frag-ordered x
    unsigned* __restrict__ cnt,       // 16 groups * 32 u32 (128B stride)
    int use_xbf)
{
    __shared__ __align__(16) __bf16 Habuf[2048 * 8];   // 32 KB h fragment tile
    __shared__ __align__(16) __bf16 Xabuf[2048 * 8];   // 32 KB x fragment tile
    __shared__ __align__(16) float  Xacc[2][4][16][64];// 32 KB xacc handoff (dbuf)
    __shared__ __align__(16) float  Gs[4][32][36];     // gate exchange

    const int tid  = threadIdx.x;
    const int lane = tid & 63;
    const int w8   = tid >> 6;             // 0..7
    const bool isrec = (w8 < 4);
    const int w    = w8 & 3;               // gate index within group
    const int bid  = blockIdx.x;
    const int mt   = bid & 15;
    const int ht   = bid >> 4;
    const int t255 = tid & 255;

    unsigned* cnt_mt = cnt + mt * 32;

    const int col  = lane & 31;
    const int half = lane >> 5;
    const int gidx = w * 512 + ht * 32 + col;
    const float bias = bih[gidx] + bhh[gidx];

    const int cm  = t255 >> 3;             // batch row in tile (rec threads)
    const int cnb = (t255 & 7) << 2;       // hidden col base (within ht tile)
    const int hid = ht * 32 + cnb;
    const size_t hwoff = ((size_t)mt * 2048 + (size_t)(hid >> 4) * 64
                          + (size_t)(cm + (((hid >> 3) & 1) << 5))) * 8 + (hid & 7);

    // role-specific B-fragments, ONE register array (64 VGPR):
    //   rec waves: W_hh frags;  x waves: W_ih frags.
    const __bf16* wsrc = wf + (isrec ? (size_t)WHALF : (size_t)0)
                       + (size_t)(w * 16 + ht) * 16384;
    v8bf wreg[32];
    #pragma unroll
    for (int k16 = 0; k16 < 32; ++k16)
        wreg[k16] = *(const v8bf*)&wsrc[k16 * 512 + lane * 8];

    float4 cv = make_float4(0.f, 0.f, 0.f, 0.f);

    // ---- prologue: x waves compute xacc(0) -> Xacc[0]
    if (!isrec) {
        if (use_xbf) {
            const __bf16* xsrc = xbf + (size_t)mt * 16384;           // ts = 0
            #pragma unroll
            for (int it = 0; it < 8; ++it) {
                const int sb = it * 256 + w * 64;
                dma16(xsrc + (size_t)(sb + lane) * 8, &Xabuf[sb * 8]);
            }
        } else {
            #pragma unroll
            for (int it = 0; it < 8; ++it) {
                const int s   = it * 256 + t255;
                const int k16 = s >> 6, ln = s & 63;
                const int r   = ln & 31;
                const int b   = mt * 32 + r;
                const int k   = k16 * 16 + ((ln >> 5) << 3);
                v8bf v;
                if (b < BATCH) {
                    const float* p  = x + (size_t)b * XROW + k;      // ts = 0
                    const float4 f0 = *(const float4*)p;
                    const float4 f1 = *(const float4*)(p + 4);
                    v[0] = (__bf16)f0.x; v[1] = (__bf16)f0.y; v[2] = (__bf16)f0.z; v[3] = (__bf16)f0.w;
                    v[4] = (__bf16)f1.x; v[5] = (__bf16)f1.y; v[6] = (__bf16)f1.z; v[7] = (__bf16)f1.w;
                } else {
                    #pragma unroll
                    for (int j = 0; j < 8; ++j) v[j] = (__bf16)0.f;
                }
                *(v8bf*)&Xabuf[s * 8] = v;
            }
        }
    }
    __syncthreads();
    if (!isrec) {
        f32x16 a0, a1;
        #pragma unroll
        for (int j = 0; j < 16; ++j) { a0[j] = 0.f; a1[j] = 0.f; }
        #pragma unroll
        for (int k16 = 0; k16 < 32; k16 += 2) {
            const v8bf x0 = *(const v8bf*)&Xabuf[(k16 * 64 + lane) * 8];
            const v8bf x1 = *(const v8bf*)&Xabuf[((k16 + 1) * 64 + lane) * 8];
            a0 = __builtin_amdgcn_mfma_f32_32x32x16_bf16(x0, wreg[k16], a0, 0, 0, 0);
            a1 = __builtin_amdgcn_mfma_f32_32x32x16_bf16(x1, wreg[k16 + 1], a1, 0, 0, 0);
        }
        #pragma unroll
        for (int r = 0; r < 16; ++r) Xacc[0][w][r][lane] = a0[r] + a1[r];
    }
    __syncthreads();

    #pragma unroll 1
    for (int t = 0; t < TSTEPS; ++t) {
        // ---- A: rec tid0 polls peers; x waves stage x(t+1)
        if (tid == 0 && t > 0) {
            const unsigned target = 16u * (unsigned)t;
            unsigned iters = 0;
            while (__hip_atomic_load(cnt_mt, __ATOMIC_RELAXED, __HIP_MEMORY_SCOPE_AGENT) < target) {
                __builtin_amdgcn_s_sleep(1);
                if (++iters > 100000000u) break;   // escape hatch: never hang
            }
        }
        if (!isrec && t + 1 < TSTEPS) {
            const int ts = t + 1;
            if (use_xbf) {
                const __bf16* xsrc = xbf + (size_t)ts * NSLOT + (size_t)mt * 16384;
                #pragma unroll
                for (int it = 0; it < 8; ++it) {
                    const int sb = it * 256 + w * 64;
                    dma16(xsrc + (size_t)(sb + lane) * 8, &Xabuf[sb * 8]);
                }
            } else {
                #pragma unroll
                for (int it = 0; it < 8; ++it) {
                    const int s   = it * 256 + t255;
                    const int k16 = s >> 6, ln = s & 63;
                    const int r   = ln & 31;
                    const int b   = mt * 32 + r;
                    const int k   = k16 * 16 + ((ln >> 5) << 3);
                    v8bf v;
                    if (b < BATCH) {
                        const float* p  = x + (size_t)b * XROW + (size_t)ts * EMBED + k;
                        const float4 f0 = *(const float4*)p;
                        const float4 f1 = *(const float4*)(p + 4);
                        v[0] = (__bf16)f0.x; v[1] = (__bf16)f0.y; v[2] = (__bf16)f0.z; v[3] = (__bf16)f0.w;
                        v[4] = (__bf16)f1.x; v[5] = (__bf16)f1.y; v[6] = (__bf16)f1.z; v[7] = (__bf16)f1.w;
                    } else {
                        #pragma unroll
                        for (int j = 0; j < 8; ++j) v[j] = (__bf16)0.f;
                    }
                    *(v8bf*)&Xabuf[s * 8] = v;
                }
            }
        }
        __syncthreads();                                  // B1: h_{t-1} ready; Xabuf staged

        if (isrec) {
            // DMA h_{t-1} frags (plain cached; lines never stale on this XCD)
            const __bf16* hsrc = (const __bf16*)(hfb + (size_t)t * SLOTB) + (size_t)mt * 16384;
            #pragma unroll
            for (int it = 0; it < 8; ++it) {
                const int sb = it * 256 + w * 64;
                dma16(hsrc + (size_t)(sb + lane) * 8, &Habuf[sb * 8]);
            }
        } else if (t + 1 < TSTEPS) {
            // xacc(t+1) concurrent with rec's h DMA (W_ih from registers)
            f32x16 a0, a1;
            #pragma unroll
            for (int j = 0; j < 16; ++j) { a0[j] = 0.f; a1[j] = 0.f; }
            #pragma unroll
            for (int k16 = 0; k16 < 32; k16 += 2) {
                const v8bf x0 = *(const v8bf*)&Xabuf[(k16 * 64 + lane) * 8];
                const v8bf x1 = *(const v8bf*)&Xabuf[((k16 + 1) * 64 + lane) * 8];
                a0 = __builtin_amdgcn_mfma_f32_32x32x16_bf16(x0, wreg[k16], a0, 0, 0, 0);
                a1 = __builtin_amdgcn_mfma_f32_32x32x16_bf16(x1, wreg[k16 + 1], a1, 0, 0, 0);
            }
            const int nb = (t + 1) & 1;
            #pragma unroll
            for (int r = 0; r < 16; ++r) Xacc[nb][w][r][lane] = a0[r] + a1[r];
        }
        __syncthreads();                                  // B2: Habuf ready; xacc(t+1) stored

        if (isrec) {
            const int cb = t & 1;
            f32x16 a0, a1;
            #pragma unroll
            for (int r = 0; r < 16; ++r) { a0[r] = Xacc[cb][w][r][lane]; a1[r] = 0.f; }
            #pragma unroll
            for (int k16 = 0; k16 < 32; k16 += 2) {
                const v8bf h0 = *(const v8bf*)&Habuf[(k16 * 64 + lane) * 8];
                const v8bf h1 = *(const v8bf*)&Habuf[((k16 + 1) * 64 + lane) * 8];
                a0 = __builtin_amdgcn_mfma_f32_32x32x16_bf16(h0, wreg[k16], a0, 0, 0, 0);
                a1 = __builtin_amdgcn_mfma_f32_32x32x16_bf16(h1, wreg[k16 + 1], a1, 0, 0, 0);
            }
            #pragma unroll
            for (int r = 0; r < 16; ++r) {
                const int mr = (r & 3) + 8 * (r >> 2) + 4 * half;
                Gs[w][mr][col] = a0[r] + a1[r] + bias;
            }
        }
        __syncthreads();                                  // B3: Gs ready

        if (isrec) {
            const float4 gi = *(const float4*)&Gs[0][cm][cnb];
            const float4 gf = *(const float4*)&Gs[1][cm][cnb];
            const float4 gg = *(const float4*)&Gs[2][cm][cnb];
            const float4 go = *(const float4*)&Gs[3][cm][cnb];
            float4 hv;
            const float i0 = sigm_(gi.x), f0 = sigm_(gf.x), g0 = tanh_(gg.x), o0 = sigm_(go.x);
            cv.x = f0 * cv.x + i0 * g0; hv.x = o0 * tanh_(cv.x);
            const float i1 = sigm_(gi.y), f1 = sigm_(gf.y), g1 = tanh_(gg.y), o1 = sigm_(go.y);
            cv.y = f1 * cv.y + i1 * g1; hv.y = o1 * tanh_(cv.y);
            const float i2 = sigm_(gi.z), f2 = sigm_(gf.z), g2 = tanh_(gg.z), o2 = sigm_(go.z);
            cv.z = f2 * cv.z + i2 * g2; hv.z = o2 * tanh_(cv.z);
            const float i3 = sigm_(gi.w), f3 = sigm_(gf.w), g3 = tanh_(gg.w), o3 = sigm_(go.w);
            cv.w = f3 * cv.w + i3 * g3; hv.w = o3 * tanh_(cv.w);
            union { unsigned long long u; __bf16 b4[4]; } z;
            z.b4[0] = (__bf16)hv.x; z.b4[1] = (__bf16)hv.y;
            z.b4[2] = (__bf16)hv.z; z.b4[3] = (__bf16)hv.w;
            store8_wt(hfb + (size_t)(t + 1) * SLOTB + hwoff * 2, z.u);
            drain_vm();                                   // write-through acked
        }
        __syncthreads();                                  // B4: all rec stores drained
        if (tid == 0)
            __hip_atomic_fetch_add(cnt_mt, 1u, __ATOMIC_RELAXED, __HIP_MEMORY_SCOPE_AGENT);
    }
}

// ---------------------------------------------------------------------------
// Deferred FC head: one launch for all (b,t). out = sigmoid(h @ Wfc^T + bfc).
// Block (t, mt): A = hf slot t+1 (frag order, DMA), B = wfcf (N padded 128).
// ---------------------------------------------------------------------------
__global__ __launch_bounds__(256) void fc_mfma(
    const char* __restrict__ hfb, const __bf16* __restrict__ wfcf,
    const float* __restrict__ bfc, float* __restrict__ out)
{
    __shared__ __align__(16) __bf16 Abuf[2048 * 8];
    __shared__ __align__(16) float  Fs[32][132];

    const int tid  = threadIdx.x;
    const int lane = tid & 63;
    const int w    = tid >> 6;
    const int t    = blockIdx.x;
    const int mt   = blockIdx.y;

    const __bf16* hsrc = (const __bf16*)(hfb + (size_t)(t + 1) * SLOTB) + (size_t)mt * 16384;
    #pragma unroll
    for (int it = 0; it < 8; ++it) {
        const int sb = it * 256 + w * 64;
        dma16(hsrc + (size_t)(sb + lane) * 8, &Abuf[sb * 8]);
    }
    __syncthreads();

    f32x16 acc;
    #pragma unroll
    for (int j = 0; j < 16; ++j) acc[j] = 0.f;
    const __bf16* wfw = wfcf + (size_t)w * 16384;
    #pragma unroll
    for (int k16 = 0; k16 < 32; ++k16) {
        const v8bf a = *(const v8bf*)&Abuf[(k16 * 64 + lane) * 8];
        const v8bf b = *(const v8bf*)&wfw[k16 * 512 + lane * 8];
        acc = __builtin_amdgcn_mfma_f32_32x32x16_bf16(a, b, acc, 0, 0, 0);
    }

    const int col = lane & 31, half = lane >> 5;
    #pragma unroll
    for (int r = 0; r < 16; ++r) {
        const int mr = (r & 3) + 8 * (r >> 2) + 4 * half;
        Fs[mr][w * 32 + col] = acc[r];
    }
    __syncthreads();

    const int mr = tid >> 3;
    const int b  = mt * 32 + mr;
    if (b < BATCH) {
        const int c0 = (tid & 7) * 16;
        float* ob = out + ((size_t)b * TSTEPS + t) * OUTF;
        #pragma unroll
        for (int j = 0; j < 4; ++j) {
            const int o = c0 + j * 4;
            if (o < OUTF) {
                const float4 v  = *(const float4*)&Fs[mr][o];
                const float4 bv = *(const float4*)&bfc[o];
                float4 r4;
                r4.x = sigm_(v.x + bv.x); r4.y = sigm_(v.y + bv.y);
                r4.z = sigm_(v.z + bv.z); r4.w = sigm_(v.w + bv.w);
                *(float4*)&ob[o] = r4;
            }
        }
    }
}

// ===========================================================================
// Fallback path (verified round-0 structure): per-step gates_cell + fc_kernel.
// Used when ws_size cannot hold the 257-slot hf ring.
// ===========================================================================
__global__ __launch_bounds__(256) void gates_cell(
    const float*  __restrict__ x,
    const __bf16* __restrict__ hbf_in,
    const __bf16* __restrict__ wf,
    const float*  __restrict__ bih, const float* __restrict__ bhh,
    float* __restrict__ c,
    float* __restrict__ h,
    __bf16* __restrict__ hbf_out,
    int t)
{
    __shared__ __bf16 Abuf[32 * 64 * 8];
    __shared__ float  Gs[4][32][36];

    const int tid  = threadIdx.x;
    const int lane = tid & 63;
    const int w    = tid >> 6;
    const int ht   = blockIdx.x;
    const int mt   = blockIdx.y;

    #pragma unroll
    for (int it = 0; it < 8; ++it) {
        const int s   = it * 256 + tid;
        const int k16 = s >> 6, ln = s & 63;
        const int r   = ln & 31;
        const int b   = mt * 32 + r;
        const int k   = k16 * 16 + ((ln >> 5) << 3);
        v8bf v;
        if (b < BATCH) {
            const float* p = x + (long)b * XROW + (long)t * EMBED + k;
            const float4 f0 = *(const float4*)p;
            const float4 f1 = *(const float4*)(p + 4);
            v[0] = (__bf16)f0.x; v[1] = (__bf16)f0.y; v[2] = (__bf16)f0.z; v[3] = (__bf16)f0.w;
            v[4] = (__bf16)f1.x; v[5] = (__bf16)f1.y; v[6] = (__bf16)f1.z; v[7] = (__bf16)f1.w;
        } else {
            #pragma unroll
            for (int j = 0; j < 8; ++j) v[j] = (__bf16)0.f;
        }
        *(v8bf*)&Abuf[s * 8] = v;
    }
    __syncthreads();

    f32x16 acc;
    #pragma unroll
    for (int j = 0; j < 16; ++j) acc[j] = 0.f;

    const __bf16* wf_g = wf + (long)((w * 16 + ht) * 32) * 64 * 8;
    #pragma unroll 4
    for (int k16 = 0; k16 < 32; ++k16) {
        const v8bf a = *(const v8bf*)&Abuf[(k16 * 64 + lane) * 8];
        const v8bf b = *(const v8bf*)&wf_g[(k16 * 64 + lane) * 8];
        acc = __builtin_amdgcn_mfma_f32_32x32x16_bf16(a, b, acc, 0, 0, 0);
    }
    __syncthreads();

    #pragma unroll
    for (int it = 0; it < 8; ++it) {
        const int s   = it * 256 + tid;
        const int k16 = s >> 6, ln = s & 63;
        const int r   = ln & 31;
        const int k   = k16 * 16 + ((ln >> 5) << 3);
        *(v8bf*)&Abuf[s * 8] = *(const v8bf*)&hbf_in[(long)(mt * 32 + r) * 512 + k];
    }
    __syncthreads();

    const __bf16* wf_h = wf + WHALF + (long)((w * 16 + ht) * 32) * 64 * 8;
    #pragma unroll 4
    for (int k16 = 0; k16 < 32; ++k16) {
        const v8bf a = *(const v8bf*)&Abuf[(k16 * 64 + lane) * 8];
        const v8bf b = *(const v8bf*)&wf_h[(k16 * 64 + lane) * 8];
        acc = __builtin_amdgcn_mfma_f32_32x32x16_bf16(a, b, acc, 0, 0, 0);
    }

    const int col  = lane & 31;
    const int half = lane >> 5;
    const int gidx = w * 512 + ht * 32 + col;
    const float bias = bih[gidx] + bhh[gidx];
    #pragma unroll
    for (int r = 0; r < 16; ++r) {
        const int m = (r & 3) + 8 * (r >> 2) + 4 * half;
        Gs[w][m][col] = acc[r] + bias;
    }
    __syncthreads();

    {
        const int m  = tid >> 3;
        const int nb = (tid & 7) << 2;
        const int b  = mt * 32 + m;
        if (b < BATCH) {
            const float4 gi = *(const float4*)&Gs[0][m][nb];
            const float4 gf = *(const float4*)&Gs[1][m][nb];
            const float4 gg = *(const float4*)&Gs[2][m][nb];
            const float4 go = *(const float4*)&Gs[3][m][nb];
            const long cix = (long)b * 512 + ht * 32 + nb;
            float4 cvv = *(const float4*)&c[cix];
            float4 hv;
            {
                const float i0 = sigm_(gi.x), f0 = sigm_(gf.x), g0 = tanh_(gg.x), o0 = sigm_(go.x);
                cvv.x = f0 * cvv.x + i0 * g0; hv.x = o0 * tanh_(cvv.x);
                const float i1 = sigm_(gi.y), f1 = sigm_(gf.y), g1 = tanh_(gg.y), o1 = sigm_(go.y);
                cvv.y = f1 * cvv.y + i1 * g1; hv.y = o1 * tanh_(cvv.y);
                const float i2 = sigm_(gi.z), f2 = sigm_(gf.z), g2 = tanh_(gg.z), o2 = sigm_(go.z);
                cvv.z = f2 * cvv.z + i2 * g2; hv.z = o2 * tanh_(cvv.z);
                const float i3 = sigm_(gi.w), f3 = sigm_(gf.w), g3 = tanh_(gg.w), o3 = sigm_(go.w);
                cvv.w = f3 * cvv.w + i3 * g3; hv.w = o3 * tanh_(cvv.w);
            }
            *(float4*)&c[cix] = cvv;
            *(float4*)&h[cix] = hv;
            union { uint2 u; __bf16 b4[4]; } z;
            z.b4[0] = (__bf16)hv.x; z.b4[1] = (__bf16)hv.y;
            z.b4[2] = (__bf16)hv.z; z.b4[3] = (__bf16)hv.w;
            *(uint2*)&hbf_out[cix] = z.u;
        }
    }
}

__global__ __launch_bounds__(256) void fc_kernel(
    const float* __restrict__ h, const float* __restrict__ Wfc,
    const float* __restrict__ bfc, float* __restrict__ out, int t)
{
    const int b    = blockIdx.x;
    const int lane = threadIdx.x & 63;
    const int w    = threadIdx.x >> 6;

    const float* hb = h + (long)b * HIDDEN + lane * 8;
    const float4 h0 = *(const float4*)(hb);
    const float4 h1 = *(const float4*)(hb + 4);
    float* outb = out + (long)b * TSTEPS * OUTF + (long)t * OUTF;

    for (int oi = 0; oi < 25; ++oi) {
        const int o = w * 25 + oi;
        const float* wr = Wfc + (long)o * HIDDEN + lane * 8;
        const float4 w0 = *(const float4*)(wr);
        const float4 w1 = *(const float4*)(wr + 4);
        float p = h0.x * w0.x + h0.y * w0.y + h0.z * w0.z + h0.w * w0.w
                + h1.x * w1.x + h1.y * w1.y + h1.z * w1.z + h1.w * w1.w;
        #pragma unroll
        for (int s = 32; s > 0; s >>= 1) p += __shfl_xor(p, s, 64);
        if (lane == 0) outb[o] = sigm_(p + bfc[o]);
    }
}

extern "C" void kernel_launch(void* const* d_in, const int* in_sizes, int n_in,
                              void* d_out, int out_size, void* d_ws, size_t ws_size,
                              hipStream_t stream) {
    const float* x   = (const float*)d_in[0];
    const float* Wih = (const float*)d_in[1];
    const float* Whh = (const float*)d_in[2];
    const float* bih = (const float*)d_in[3];
    const float* bhh = (const float*)d_in[4];
    const float* Wfc = (const float*)d_in[5];
    const float* bfc = (const float*)d_in[6];
    float* out = (float*)d_out;

    // fast-path ws: [cnt 2KB][hf 257*SLOTB][wf 4MB][wfc 128KB][xbf 128MB opt]
    const size_t HF_BYTES = (size_t)257 * SLOTB;
    const size_t FAST_WS  = 2048 + HF_BYTES + (size_t)4 * WHALF + 131072;
    const size_t XBF_WS   = FAST_WS + (size_t)TSTEPS * NSLOT * 2;

    if (ws_size >= FAST_WS) {
        char* p = (char*)d_ws;
        unsigned* cnt  = (unsigned*)p;
        char*     hfb  = p + 2048;
        __bf16*   wf   = (__bf16*)(p + 2048 + HF_BYTES);
        __bf16*   wfcf = wf + 2 * WHALF;
        __bf16*   xbf  = (__bf16*)(p + FAST_WS);
        const int use_xbf = (ws_size >= XBF_WS) ? 1 : 0;

        // zero barrier counters + hf slot 0 data region (h_{-1} = 0)
        hipMemsetAsync(d_ws, 0, 2048 + (size_t)NSLOT * 2, stream);

        convert_w<<<1024, 256, 0, stream>>>(Wih, Whh, wf);
        convert_wfc<<<32, 256, 0, stream>>>(Wfc, wfcf);
        if (use_xbf) convert_x<<<32768, 256, 0, stream>>>(x, xbf);

        lstm_persist<<<GRIDP, 512, 0, stream>>>(x, wf, bih, bhh, hfb, xbf, cnt, use_xbf);
        fc_mfma<<<dim3(TSTEPS, 16), 256, 0, stream>>>(hfb, wfcf, bfc, out);
    } else {
        // fallback ws: [c fp32 1MB][hbfA 0.5MB][hbfB 0.5MB][h fp32 1MB][wf bf16 4MB]
        float*  c    = (float*)d_ws;
        __bf16* hbfA = (__bf16*)(c + MPAD * HIDDEN);
        __bf16* hbfB = hbfA + MPAD * HIDDEN;
        float*  h    = (float*)(hbfB + MPAD * HIDDEN);
        __bf16* wf   = (__bf16*)(h + MPAD * HIDDEN);

        hipMemsetAsync(d_ws, 0, (size_t)MPAD * HIDDEN * 4 + (size_t)2 * MPAD * HIDDEN * 2, stream);
        convert_w<<<1024, 256, 0, stream>>>(Wih, Whh, wf);

        const dim3 ggrid(16, 16);
        for (int t = 0; t < TSTEPS; ++t) {
            const __bf16* hin  = (t & 1) ? hbfB : hbfA;
            __bf16*       hout = (t & 1) ? hbfA : hbfB;
            gates_cell<<<ggrid, 256, 0, stream>>>(x, hin, wf, bih, bhh, c, h, hout, t);
            fc_kernel<<<BATCH, 256, 0, stream>>>(h, Wfc, bfc, out, t);
        }
    }
}